// Round 1
// baseline (556.336 us; speedup 1.0000x reference)
//
#include <hip/hip_runtime.h>
#include <math.h>

#define BATCH 8
#define KQ 256
#define DIM 50257
#define KNN 8
#define N_CLASS 4
#define INV_T 20.0f   // 1/0.05

// ---------------- kernel 1: log of logits into workspace ----------------
__global__ __launch_bounds__(256) void log_logits_kernel(
        const float* __restrict__ logits, float* __restrict__ ll, int n) {
    int i = blockIdx.x * 256 + threadIdx.x;
    if (i < n) ll[i] = __logf(logits[i]);
}

// ---------------- kernel 2: per-(b,k) KL distance reduction ----------------
// grid = B*K blocks, 256 threads. Reads the 412MB queue_anchor stream with
// aligned float4 (peel to fix the odd-DIM row misalignment); log_logits is
// L2-resident and read scalar.
__global__ __launch_bounds__(256) void dists_kernel(
        const float* __restrict__ qa, const float* __restrict__ ll,
        float* __restrict__ dists) {
    const int bk = blockIdx.x;          // b*256 + k
    const int b  = bk >> 8;
    const float* __restrict__ qrow = qa + (size_t)bk * DIM;
    const float* __restrict__ lrow = ll + (size_t)b * DIM;

    // row start float-index = bk*50257 ≡ bk (mod 4)  -> peel to 16B alignment
    const int peel = (4 - (bk & 3)) & 3;
    const int nv   = (DIM - peel) >> 2;          // aligned float4 count
    const int tail = peel + nv * 4;              // first tail scalar index
    const int t = threadIdx.x;

    float ax = 0.f, ay = 0.f, az = 0.f, aw = 0.f;
    const float4* __restrict__ q4 = (const float4*)(qrow + peel);
    const float*  __restrict__ lb = lrow + peel;
    for (int i = t; i < nv; i += 256) {
        float4 q = q4[i];
        int j = i << 2;
        ax += q.x * (__logf(q.x) - lb[j]);
        ay += q.y * (__logf(q.y) - lb[j + 1]);
        az += q.z * (__logf(q.z) - lb[j + 2]);
        aw += q.w * (__logf(q.w) - lb[j + 3]);
    }
    float s = (ax + ay) + (az + aw);

    // peel scalars (indices [0, peel)) and tail scalars (indices [tail, DIM))
    if (t < peel) {
        float q = qrow[t];
        s += q * (__logf(q) - lrow[t]);
    }
    int tn = DIM - tail;                          // 0..3
    if (t >= 4 && t < 4 + tn) {
        int d = tail + (t - 4);
        float q = qrow[d];
        s += q * (__logf(q) - lrow[d]);
    }

    // wave reduce (64 lanes) then cross-wave via LDS
    for (int o = 32; o > 0; o >>= 1) s += __shfl_xor(s, o, 64);
    __shared__ float part[4];
    if ((t & 63) == 0) part[t >> 6] = s;
    __syncthreads();
    if (t == 0) {
        float tot = (part[0] + part[1]) + (part[2] + part[3]);
        dists[bk] = tot * (1.0f / (float)DIM);
    }
}

// ---------------- kernel 3: top-8 + softmax + class scatter ----------------
// one wave per batch row; iterative argmax, tie -> lower index (lax.top_k).
__global__ __launch_bounds__(64) void topk_kernel(
        const float* __restrict__ dists, const int* __restrict__ labels,
        float* __restrict__ out) {
    const int b = blockIdx.x;
    const int lane = threadIdx.x;
    const int base = lane * 4;
    const float* __restrict__ drow = dists + b * KQ;

    float v[4];
    #pragma unroll
    for (int j = 0; j < 4; ++j) v[j] = -INV_T * drow[base + j];

    float topv[KNN]; int topi[KNN];
    #pragma unroll
    for (int it = 0; it < KNN; ++it) {
        float lv = v[0]; int li = base;
        #pragma unroll
        for (int j = 1; j < 4; ++j)
            if (v[j] > lv || (v[j] == lv && base + j < li)) { lv = v[j]; li = base + j; }
        // full-wave argmax via xor butterfly; all lanes converge
        #pragma unroll
        for (int o = 32; o > 0; o >>= 1) {
            float ov = __shfl_xor(lv, o, 64);
            int   oi = __shfl_xor(li, o, 64);
            if (ov > lv || (ov == lv && oi < li)) { lv = ov; li = oi; }
        }
        topv[it] = lv; topi[it] = li;
        if (li >= base && li < base + 4) v[li - base] = -INFINITY;
    }

    if (lane == 0) {
        float m = topv[0];                 // max (sorted descending)
        float w[KNN], sum = 0.f;
        #pragma unroll
        for (int i = 0; i < KNN; ++i) { w[i] = __expf(topv[i] - m); sum += w[i]; }
        float p[N_CLASS] = {0.f, 0.f, 0.f, 0.f};
        #pragma unroll
        for (int i = 0; i < KNN; ++i) p[labels[b * KQ + topi[i]]] += w[i];
        float inv = 1.0f / sum;
        #pragma unroll
        for (int c = 0; c < N_CLASS; ++c) out[b * N_CLASS + c] = p[c] * inv;
    }
}

extern "C" void kernel_launch(void* const* d_in, const int* in_sizes, int n_in,
                              void* d_out, int out_size, void* d_ws, size_t ws_size,
                              hipStream_t stream) {
    const float* logits = (const float*)d_in[0];   // [B, DIM]
    const float* qa     = (const float*)d_in[1];   // [B, K, DIM]
    const int*   labels = (const int*)d_in[2];     // [B, K]
    float* out = (float*)d_out;                    // [B, N_CLASS]

    // ws layout: log_logits [B*DIM] f32, then dists [B*K] f32
    float* ll    = (float*)d_ws;
    float* dists = ll + (size_t)BATCH * DIM;       // 402056 floats in

    const int n_ll = BATCH * DIM;
    log_logits_kernel<<<(n_ll + 255) / 256, 256, 0, stream>>>(logits, ll, n_ll);
    dists_kernel<<<BATCH * KQ, 256, 0, stream>>>(qa, ll, dists);
    topk_kernel<<<BATCH, 64, 0, stream>>>(dists, labels, out);
}